// Round 6
// baseline (953.224 us; speedup 1.0000x reference)
//
#include <hip/hip_runtime.h>
#include <hip/hip_bf16.h>
#include <stdint.h>

typedef unsigned short u16;
typedef uint32_t u32;
typedef unsigned long long u64;

__device__ __forceinline__ float bf2f(u16 u) {
    return __uint_as_float(((uint32_t)u) << 16);
}
__device__ __forceinline__ u16 f2bf(float f) {
    uint32_t u = __float_as_uint(f);
    uint32_t r = u + 0x7fffu + ((u >> 16) & 1u);
    return (u16)(r >> 16);
}

__device__ __forceinline__ float ldf(const float* p) { return *p; }
__device__ __forceinline__ float ldf(const u16* p) { return bf2f(*p); }

#define DEG_SCALE 4294967296.0f           // 2^32
#define DEG_INV 2.3283064365386963e-10f   // 2^-32

// bucket partition geometry (src index must fit 17 bits: n <= 131072)
#define BSHIFT 9
#define BSIZE 512
#define CAP 19456      // per-bucket capacity; mean E/NB ~= 16326, 24 sigma headroom

// ---------------- init bucket write pointers ----------------
__global__ void k_init0(u32* bwptr, int NB) {
    int t = threadIdx.x;
    if (t < NB) bwptr[t] = (u32)t * CAP;
}

// ---------------- 32-row GEMM tile as a device function (shared by both layers) ----------------
template <typename TIn>
__device__ __forceinline__ void gemm_block(const TIn* __restrict__ A, const float* __restrict__ W,
                                           u16* __restrict__ outp, int n, int bid) {
    __shared__ float As[32][128];
    __shared__ float Ws[32][128];
    int t = threadIdx.x;
    int row0 = bid * 32;

    if constexpr (sizeof(TIn) == 2) {
        for (int i = t; i < 32 * 64; i += 256) {
            int r = i >> 6, c2 = i & 63;
            int gr = row0 + r;
            uint32_t u = (gr < n) ? *reinterpret_cast<const uint32_t*>(&A[(size_t)gr * 128 + 2 * c2]) : 0u;
            As[r][2 * c2] = bf2f((u16)(u & 0xffff));
            As[r][2 * c2 + 1] = bf2f((u16)(u >> 16));
        }
    } else {
        for (int i = t; i < 32 * 128; i += 256) {
            int r = i >> 7, c = i & 127;
            int gr = row0 + r;
            As[r][c] = (gr < n) ? ldf(&A[(size_t)gr * 128 + c]) : 0.0f;
        }
    }

    float acc[4][4];
#pragma unroll
    for (int i = 0; i < 4; i++)
#pragma unroll
        for (int j = 0; j < 4; j++) acc[i][j] = 0.0f;

    int c0 = (t & 31) * 4;
    int r0 = (t >> 5) * 4;

    for (int kt = 0; kt < 128; kt += 32) {
        __syncthreads();
        for (int i = t; i < 32 * 128; i += 256) {
            int kk = i >> 7, c = i & 127;
            Ws[kk][c] = W[(size_t)(kt + kk) * 128 + c];
        }
        __syncthreads();
#pragma unroll
        for (int kk = 0; kk < 32; kk += 4) {
            float w0[4], w1[4], w2[4], w3[4];
            *(float4*)w0 = *(const float4*)&Ws[kk + 0][c0];
            *(float4*)w1 = *(const float4*)&Ws[kk + 1][c0];
            *(float4*)w2 = *(const float4*)&Ws[kk + 2][c0];
            *(float4*)w3 = *(const float4*)&Ws[kk + 3][c0];
#pragma unroll
            for (int i = 0; i < 4; i++) {
                float a[4];
                *(float4*)a = *(const float4*)&As[r0 + i][kt + kk];
#pragma unroll
                for (int j = 0; j < 4; j++) {
                    acc[i][j] = fmaf(a[0], w0[j], acc[i][j]);
                    acc[i][j] = fmaf(a[1], w1[j], acc[i][j]);
                    acc[i][j] = fmaf(a[2], w2[j], acc[i][j]);
                    acc[i][j] = fmaf(a[3], w3[j], acc[i][j]);
                }
            }
        }
    }

#pragma unroll
    for (int i = 0; i < 4; i++) {
        int gr = row0 + r0 + i;
        if (gr < n) {
            ushort4 o;
            o.x = f2bf(acc[i][0]);
            o.y = f2bf(acc[i][1]);
            o.z = f2bf(acc[i][2]);
            o.w = f2bf(acc[i][3]);
            *reinterpret_cast<ushort4*>(&outp[(size_t)gr * 128 + c0]) = o;
        }
    }
}

// ---------------- fused: [gemm1 | edge partition] role by bid%16 ----------------
// r==0 -> partition block g (Gp total); r!=0 -> gemm block g*15+(r-1) (Gg total)
__global__ __launch_bounds__(256) void k_part_gemm(const float* __restrict__ x, const float* __restrict__ W1,
                                                   u16* __restrict__ tbuf, int n, int Gg,
                                                   const int* __restrict__ src, const int* __restrict__ dst,
                                                   const float* __restrict__ ew,
                                                   u32* bwptr, u64* __restrict__ ebuf,
                                                   int E, int Gp, int EPB, int NB) {
    int bid = blockIdx.x;
    int g = bid >> 4;
    int r = bid & 15;
    if (r != 0) {
        int gb = g * 15 + (r - 1);
        if (gb < Gg) gemm_block<float>(x, W1, tbuf, n, gb);
        return;
    }
    if (g >= Gp) return;
    __shared__ u32 hist[256];
    __shared__ u32 base[256];
    int t = threadIdx.x;
    if (t < NB) hist[t] = 0;
    __syncthreads();
    int e0 = g * EPB;
    int e1 = min(e0 + EPB, E);
    for (int e = e0 + t; e < e1; e += 256) {
        atomicAdd(&hist[dst[e] >> BSHIFT], 1u);
    }
    __syncthreads();
    if (t < NB) {
        base[t] = atomicAdd(&bwptr[t], hist[t]);
        hist[t] = 0;
    }
    __syncthreads();
    for (int e = e0 + t; e < e1; e += 256) {
        int d = dst[e];
        int b = d >> BSHIFT;
        u32 pos = base[b] + atomicAdd(&hist[b], 1u);
        u32 w0 = (u32)src[e] | ((u32)(d & (BSIZE - 1)) << 17);
        ebuf[pos] = (u64)w0 | ((u64)__float_as_uint(ew[e]) << 32);
    }
}

// ---------------- per-bucket degcnt in LDS (zero global atomics) ----------------
__global__ __launch_bounds__(512) void k_bdegcnt(const u64* __restrict__ ebuf, const u32* __restrict__ bwptr,
                                                 u64* __restrict__ packed, int n) {
    __shared__ u64 acc[BSIZE];
    int b = blockIdx.x;
    int t = threadIdx.x;
    for (int i = t; i < BSIZE; i += 512) acc[i] = 0;
    __syncthreads();
    int cnt = (int)(bwptr[b] - (u32)b * CAP);
    const u64* eb = ebuf + (size_t)b * CAP;
    for (int e = t; e < cnt; e += 512) {
        u64 w = eb[e];
        int dlow = ((u32)w >> 17) & (BSIZE - 1);
        float wv = __uint_as_float((u32)(w >> 32));
        atomicAdd(&acc[dlow], (1ull << 48) | (u64)(wv * DEG_SCALE));
    }
    __syncthreads();
    int node0 = b << BSHIFT;
    for (int i = t; i < BSIZE; i += 512) {
        int node = node0 + i;
        if (node < n) packed[node] = acc[i] + (1ull << 32);  // + self-loop (deg 1.0)
    }
}

// ---------------- fused dinv + block-level exclusive scan of cnt ----------------
__global__ void k_dinv_scan(const u64* __restrict__ packed, float* dinv, int* rowptr, int* bsum, int n) {
    __shared__ int s[256];
    int t = threadIdx.x;
    int i = blockIdx.x * 256 + t;
    u64 pk = (i < n) ? packed[i] : 0;
    if (i < n) {
        float deg = (float)(pk & 0xFFFFFFFFFFFFull) * DEG_INV;
        dinv[i] = rsqrtf(deg);
    }
    int v = (int)(pk >> 48);
    s[t] = v;
    __syncthreads();
    for (int off = 1; off < 256; off <<= 1) {
        int x = (t >= off) ? s[t - off] : 0;
        __syncthreads();
        s[t] += x;
        __syncthreads();
    }
    if (i < n) rowptr[i] = s[t] - v;  // exclusive
    if (t == 255) bsum[blockIdx.x] = s[255];
}

__global__ void k_scan_sums(int* bsum, int nb) {
    __shared__ int s[512];
    int t = threadIdx.x;
    int v = (t < nb) ? bsum[t] : 0;
    s[t] = v;
    __syncthreads();
    for (int off = 1; off < 512; off <<= 1) {
        int x = (t >= off) ? s[t - off] : 0;
        __syncthreads();
        s[t] += x;
        __syncthreads();
    }
    if (t < nb) bsum[t] = s[t] - v;  // exclusive
}

__global__ void k_scan_add(int* rowptr, const int* __restrict__ bsum, int n) {
    int i = blockIdx.x * 256 + threadIdx.x;
    if (i < n) rowptr[i] += bsum[blockIdx.x];
}

// ---------------- per-bucket scatter into CSR (L2-local rec writes) ----------------
__global__ __launch_bounds__(512) void k_bscatter(const u64* __restrict__ ebuf, const u32* __restrict__ bwptr,
                                                  const int* __restrict__ rowptr, const float* __restrict__ dinv,
                                                  int2* __restrict__ rec, int n) {
    __shared__ u32 fill[BSIZE];
    __shared__ int rp[BSIZE];
    __shared__ float din[BSIZE];
    int b = blockIdx.x;
    int t = threadIdx.x;
    int node0 = b << BSHIFT;
    for (int i = t; i < BSIZE; i += 512) {
        int node = node0 + i;
        fill[i] = 0;
        rp[i] = (node < n) ? rowptr[node] : 0;
        din[i] = (node < n) ? dinv[node] : 0.f;
    }
    __syncthreads();
    int cnt = (int)(bwptr[b] - (u32)b * CAP);
    const u64* eb = ebuf + (size_t)b * CAP;
    for (int e = t; e < cnt; e += 512) {
        u64 w = eb[e];
        u32 lo = (u32)w;
        int s = lo & 0x1FFFF;
        int dlow = (lo >> 17) & (BSIZE - 1);
        float ewv = __uint_as_float((u32)(w >> 32));
        float nrm = dinv[s] * ewv * din[dlow];
        int pos = rp[dlow] + (int)atomicAdd(&fill[dlow], 1u);
        rec[pos] = make_int2(s, __float_as_int(nrm));
    }
}

// ---------------- standalone gemm (layer 2) ----------------
template <typename TIn>
__global__ __launch_bounds__(256) void k_gemm(const TIn* __restrict__ A, const float* __restrict__ W,
                                              u16* __restrict__ outp, int n) {
    gemm_block<TIn>(A, W, outp, n, blockIdx.x);
}

// ---------------- aggregation: wave per node, half-wave per edge, lane = 4 channels ----------------
// MODE 0: write relu(agg)+bias to hout (bf16).  MODE 1: fused final FC -> out.
template <int MODE>
__global__ __launch_bounds__(256) void k_agg(const u16* __restrict__ t, const int2* __restrict__ rec,
                                             const int* __restrict__ rowptr, const u64* __restrict__ packed,
                                             const float* __restrict__ dinv, const float* __restrict__ bias,
                                             u16* __restrict__ hout,
                                             const float* __restrict__ action, const float* __restrict__ Wfc,
                                             const float* __restrict__ bfc, float* __restrict__ out, int n) {
    int node = blockIdx.x * 4 + (threadIdx.x >> 6);
    if (node >= n) return;
    int lane = threadIdx.x & 63;
    int half = lane >> 5;
    int c4 = (lane & 31) * 4;
    int base = rowptr[node];
    int m = (int)(packed[node] >> 48);

    float4 acc = make_float4(0.f, 0.f, 0.f, 0.f);
    int e = 0;
    for (; e + 8 <= m; e += 8) {
        int2 r0 = rec[base + e + 0 + half];
        int2 r1 = rec[base + e + 2 + half];
        int2 r2 = rec[base + e + 4 + half];
        int2 r3 = rec[base + e + 6 + half];
        ushort4 g0 = *reinterpret_cast<const ushort4*>(&t[(size_t)r0.x * 128 + c4]);
        ushort4 g1 = *reinterpret_cast<const ushort4*>(&t[(size_t)r1.x * 128 + c4]);
        ushort4 g2 = *reinterpret_cast<const ushort4*>(&t[(size_t)r2.x * 128 + c4]);
        ushort4 g3 = *reinterpret_cast<const ushort4*>(&t[(size_t)r3.x * 128 + c4]);
        float n0 = __int_as_float(r0.y), n1 = __int_as_float(r1.y);
        float n2 = __int_as_float(r2.y), n3 = __int_as_float(r3.y);
        acc.x = fmaf(n0, bf2f(g0.x), acc.x); acc.y = fmaf(n0, bf2f(g0.y), acc.y);
        acc.z = fmaf(n0, bf2f(g0.z), acc.z); acc.w = fmaf(n0, bf2f(g0.w), acc.w);
        acc.x = fmaf(n1, bf2f(g1.x), acc.x); acc.y = fmaf(n1, bf2f(g1.y), acc.y);
        acc.z = fmaf(n1, bf2f(g1.z), acc.z); acc.w = fmaf(n1, bf2f(g1.w), acc.w);
        acc.x = fmaf(n2, bf2f(g2.x), acc.x); acc.y = fmaf(n2, bf2f(g2.y), acc.y);
        acc.z = fmaf(n2, bf2f(g2.z), acc.z); acc.w = fmaf(n2, bf2f(g2.w), acc.w);
        acc.x = fmaf(n3, bf2f(g3.x), acc.x); acc.y = fmaf(n3, bf2f(g3.y), acc.y);
        acc.z = fmaf(n3, bf2f(g3.z), acc.z); acc.w = fmaf(n3, bf2f(g3.w), acc.w);
    }
    for (; e + 2 <= m; e += 2) {
        int2 r = rec[base + e + half];
        ushort4 g = *reinterpret_cast<const ushort4*>(&t[(size_t)r.x * 128 + c4]);
        float nn = __int_as_float(r.y);
        acc.x = fmaf(nn, bf2f(g.x), acc.x); acc.y = fmaf(nn, bf2f(g.y), acc.y);
        acc.z = fmaf(nn, bf2f(g.z), acc.z); acc.w = fmaf(nn, bf2f(g.w), acc.w);
    }
    if (e < m && half == 0) {
        int2 r = rec[base + e];
        ushort4 g = *reinterpret_cast<const ushort4*>(&t[(size_t)r.x * 128 + c4]);
        float nn = __int_as_float(r.y);
        acc.x = fmaf(nn, bf2f(g.x), acc.x); acc.y = fmaf(nn, bf2f(g.y), acc.y);
        acc.z = fmaf(nn, bf2f(g.z), acc.z); acc.w = fmaf(nn, bf2f(g.w), acc.w);
    }
    acc.x += __shfl_xor(acc.x, 32);
    acc.y += __shfl_xor(acc.y, 32);
    acc.z += __shfl_xor(acc.z, 32);
    acc.w += __shfl_xor(acc.w, 32);

    if (half == 0) {
        float di = dinv[node];
        float sdi = di * di;
        ushort4 sv = *reinterpret_cast<const ushort4*>(&t[(size_t)node * 128 + c4]);
        acc.x = fmaf(sdi, bf2f(sv.x), acc.x);
        acc.y = fmaf(sdi, bf2f(sv.y), acc.y);
        acc.z = fmaf(sdi, bf2f(sv.z), acc.z);
        acc.w = fmaf(sdi, bf2f(sv.w), acc.w);
        float4 b = *reinterpret_cast<const float4*>(&bias[c4]);
        acc.x = fmaxf(acc.x + b.x, 0.0f);
        acc.y = fmaxf(acc.y + b.y, 0.0f);
        acc.z = fmaxf(acc.z + b.z, 0.0f);
        acc.w = fmaxf(acc.w + b.w, 0.0f);
        if (MODE == 0) {
            ushort4 o;
            o.x = f2bf(acc.x); o.y = f2bf(acc.y); o.z = f2bf(acc.z); o.w = f2bf(acc.w);
            *reinterpret_cast<ushort4*>(&hout[(size_t)node * 128 + c4]) = o;
        } else {
            float4 w = *reinterpret_cast<const float4*>(&Wfc[c4]);
            float v = acc.x * w.x + acc.y * w.y + acc.z * w.z + acc.w * w.w;
#pragma unroll
            for (int off = 16; off >= 1; off >>= 1) v += __shfl_down(v, off, 32);
            if (lane == 0) out[node] = v + action[node] * Wfc[128] + bfc[0];
        }
    }
}

extern "C" void kernel_launch(void* const* d_in, const int* in_sizes, int n_in,
                              void* d_out, int out_size, void* d_ws, size_t ws_size,
                              hipStream_t stream) {
    const float* x = (const float*)d_in[0];
    const int* ei = (const int*)d_in[1];
    const float* ew = (const float*)d_in[2];
    const float* action = (const float*)d_in[3];
    const float* W1 = (const float*)d_in[4];
    const float* b1 = (const float*)d_in[5];
    const float* W2 = (const float*)d_in[6];
    const float* b2 = (const float*)d_in[7];
    const float* Wfc = (const float*)d_in[8];
    const float* bfc = (const float*)d_in[9];
    float* out = (float*)d_out;

    int n = in_sizes[0] / 128;
    int E = in_sizes[2];
    const int* src = ei;
    const int* dst = ei + E;

    char* p = (char*)d_ws;
    auto carve = [&](size_t bytes) -> char* {
        char* q = p;
        p += (bytes + 255) & ~(size_t)255;
        return q;
    };
    int NB = (n + BSIZE - 1) >> BSHIFT;      // 196 buckets
    u64* packed = (u64*)carve((size_t)n * 8);
    float* dinv = (float*)carve((size_t)n * 4);
    int* rowptr = (int*)carve((size_t)n * 4);
    int* bsum = (int*)carve(1024 * 4);
    u32* bwptr = (u32*)carve((size_t)NB * 4);
    u64* ebuf = (u64*)carve((size_t)NB * CAP * 8);
    int2* rec = (int2*)carve(((size_t)E + 16) * 8);
    u16* tbuf = (u16*)carve((size_t)n * 128 * 2);
    u16* hbuf = (u16*)carve((size_t)n * 128 * 2);

    int nb = (n + 255) / 256;
    int Gg = (n + 31) / 32;                  // 3125 gemm blocks
    int Gp = (Gg + 14) / 15;                 // 209 partition blocks (1:15 interleave)
    int EPB = (E + Gp - 1) / Gp;             // edges per partition block

    k_init0<<<1, 256, 0, stream>>>(bwptr, NB);
    k_part_gemm<<<Gp * 16, 256, 0, stream>>>(x, W1, tbuf, n, Gg, src, dst, ew,
                                             bwptr, ebuf, E, Gp, EPB, NB);
    k_bdegcnt<<<NB, 512, 0, stream>>>(ebuf, bwptr, packed, n);
    k_dinv_scan<<<nb, 256, 0, stream>>>(packed, dinv, rowptr, bsum, n);
    k_scan_sums<<<1, 512, 0, stream>>>(bsum, nb);
    k_scan_add<<<nb, 256, 0, stream>>>(rowptr, bsum, n);
    k_bscatter<<<NB, 512, 0, stream>>>(ebuf, bwptr, rowptr, dinv, rec, n);

    k_agg<0><<<(n + 3) / 4, 256, 0, stream>>>(tbuf, rec, rowptr, packed, dinv, b1, hbuf,
                                              nullptr, nullptr, nullptr, nullptr, n);
    k_gemm<u16><<<(n + 31) / 32, 256, 0, stream>>>(hbuf, W2, tbuf, n);
    k_agg<1><<<(n + 3) / 4, 256, 0, stream>>>(tbuf, rec, rowptr, packed, dinv, b2, nullptr,
                                              action, Wfc, bfc, out, n);
}

// Round 8
// 561.342 us; speedup vs baseline: 1.6981x; 1.6981x over previous
//
#include <hip/hip_runtime.h>
#include <hip/hip_bf16.h>
#include <stdint.h>

typedef unsigned short u16;
typedef uint32_t u32;
typedef unsigned long long u64;

__device__ __forceinline__ float bf2f(u16 u) {
    return __uint_as_float(((uint32_t)u) << 16);
}
__device__ __forceinline__ u16 f2bf(float f) {
    uint32_t u = __float_as_uint(f);
    uint32_t r = u + 0x7fffu + ((u >> 16) & 1u);
    return (u16)(r >> 16);
}

__device__ __forceinline__ float ldf(const float* p) { return *p; }
__device__ __forceinline__ float ldf(const u16* p) { return bf2f(*p); }

#define DEG_SCALE 4294967296.0f           // 2^32
#define DEG_INV 2.3283064365386963e-10f   // 2^-32

// bucket partition geometry (src index must fit 17 bits: n <= 131072)
#define BSHIFT 9
#define BSIZE 512
#define CAP 19456      // per-bucket capacity; mean E/NB ~= 16326, 24 sigma headroom

// ---------------- init bucket write pointers ----------------
__global__ void k_init0(u32* bwptr, int NB) {
    int t = threadIdx.x;
    if (t < NB) bwptr[t] = (u32)t * CAP;
}

// ---------------- 32-row GEMM tile on caller-provided 32KB LDS ----------------
template <typename TIn>
__device__ __forceinline__ void gemm_block(float* smem, const TIn* __restrict__ A,
                                           const float* __restrict__ W,
                                           u16* __restrict__ outp, int n, int bid) {
    float (*As)[128] = (float(*)[128])smem;             // 16KB
    float (*Ws)[128] = (float(*)[128])(smem + 32 * 128); // 16KB
    int t = threadIdx.x;
    int row0 = bid * 32;

    if constexpr (sizeof(TIn) == 2) {
        for (int i = t; i < 32 * 64; i += 256) {
            int r = i >> 6, c2 = i & 63;
            int gr = row0 + r;
            uint32_t u = (gr < n) ? *reinterpret_cast<const uint32_t*>(&A[(size_t)gr * 128 + 2 * c2]) : 0u;
            As[r][2 * c2] = bf2f((u16)(u & 0xffff));
            As[r][2 * c2 + 1] = bf2f((u16)(u >> 16));
        }
    } else {
        for (int i = t; i < 32 * 128; i += 256) {
            int r = i >> 7, c = i & 127;
            int gr = row0 + r;
            As[r][c] = (gr < n) ? ldf(&A[(size_t)gr * 128 + c]) : 0.0f;
        }
    }

    float acc[4][4];
#pragma unroll
    for (int i = 0; i < 4; i++)
#pragma unroll
        for (int j = 0; j < 4; j++) acc[i][j] = 0.0f;

    int c0 = (t & 31) * 4;
    int r0 = (t >> 5) * 4;

    for (int kt = 0; kt < 128; kt += 32) {
        __syncthreads();
        for (int i = t; i < 32 * 128; i += 256) {
            int kk = i >> 7, c = i & 127;
            Ws[kk][c] = W[(size_t)(kt + kk) * 128 + c];
        }
        __syncthreads();
#pragma unroll
        for (int kk = 0; kk < 32; kk += 4) {
            float w0[4], w1[4], w2[4], w3[4];
            *(float4*)w0 = *(const float4*)&Ws[kk + 0][c0];
            *(float4*)w1 = *(const float4*)&Ws[kk + 1][c0];
            *(float4*)w2 = *(const float4*)&Ws[kk + 2][c0];
            *(float4*)w3 = *(const float4*)&Ws[kk + 3][c0];
#pragma unroll
            for (int i = 0; i < 4; i++) {
                float a[4];
                *(float4*)a = *(const float4*)&As[r0 + i][kt + kk];
#pragma unroll
                for (int j = 0; j < 4; j++) {
                    acc[i][j] = fmaf(a[0], w0[j], acc[i][j]);
                    acc[i][j] = fmaf(a[1], w1[j], acc[i][j]);
                    acc[i][j] = fmaf(a[2], w2[j], acc[i][j]);
                    acc[i][j] = fmaf(a[3], w3[j], acc[i][j]);
                }
            }
        }
    }

#pragma unroll
    for (int i = 0; i < 4; i++) {
        int gr = row0 + r0 + i;
        if (gr < n) {
            ushort4 o;
            o.x = f2bf(acc[i][0]);
            o.y = f2bf(acc[i][1]);
            o.z = f2bf(acc[i][2]);
            o.w = f2bf(acc[i][3]);
            *reinterpret_cast<ushort4*>(&outp[(size_t)gr * 128 + c0]) = o;
        }
    }
}

// ---------------- fused: [gemm1 | edge partition], UNIFORM work, 3:2 role mix ----------------
// group of 5 blocks: r in {0,1,2} -> gemm block 3g+r; r in {3,4} -> partition block 2g+(r-3)
__global__ __launch_bounds__(256) void k_part_gemm(const float* __restrict__ x, const float* __restrict__ W1,
                                                   u16* __restrict__ tbuf, int n, int Gg,
                                                   const int* __restrict__ src, const int* __restrict__ dst,
                                                   const float* __restrict__ ew,
                                                   u32* bwptr, u64* __restrict__ ebuf,
                                                   int E, int EPB, int NB) {
    __shared__ float smem[2 * 32 * 128];   // 32KB, unioned across roles
    int bid = blockIdx.x;
    int g = bid / 5;
    int r = bid - g * 5;
    if (r < 3) {
        int gb = 3 * g + r;
        if (gb < Gg) gemm_block<float>(smem, x, W1, tbuf, n, gb);
        return;
    }
    int pb = 2 * g + (r - 3);
    u32* hist = (u32*)smem;
    u32* base = (u32*)smem + 256;
    int t = threadIdx.x;
    if (t < NB) hist[t] = 0;
    __syncthreads();
    int e0 = pb * EPB;
    int e1 = min(e0 + EPB, E);
    if (e0 >= E) return;
    for (int e = e0 + t; e < e1; e += 256) {
        atomicAdd(&hist[dst[e] >> BSHIFT], 1u);
    }
    __syncthreads();
    if (t < NB) {
        base[t] = atomicAdd(&bwptr[t], hist[t]);
        hist[t] = 0;
    }
    __syncthreads();
    for (int e = e0 + t; e < e1; e += 256) {
        int d = dst[e];
        int b = d >> BSHIFT;
        u32 pos = base[b] + atomicAdd(&hist[b], 1u);
        u32 w0 = (u32)src[e] | ((u32)(d & (BSIZE - 1)) << 17);
        ebuf[pos] = (u64)w0 | ((u64)__float_as_uint(ew[e]) << 32);
    }
}

// ---------------- per-bucket degcnt in LDS (zero global atomics) ----------------
__global__ __launch_bounds__(512) void k_bdegcnt(const u64* __restrict__ ebuf, const u32* __restrict__ bwptr,
                                                 u64* __restrict__ packed, int n) {
    __shared__ u64 acc[BSIZE];
    int b = blockIdx.x;
    int t = threadIdx.x;
    for (int i = t; i < BSIZE; i += 512) acc[i] = 0;
    __syncthreads();
    int cnt = (int)(bwptr[b] - (u32)b * CAP);
    const u64* eb = ebuf + (size_t)b * CAP;
    for (int e = t; e < cnt; e += 512) {
        u64 w = eb[e];
        int dlow = ((u32)w >> 17) & (BSIZE - 1);
        float wv = __uint_as_float((u32)(w >> 32));
        atomicAdd(&acc[dlow], (1ull << 48) | (u64)(wv * DEG_SCALE));
    }
    __syncthreads();
    int node0 = b << BSHIFT;
    for (int i = t; i < BSIZE; i += 512) {
        int node = node0 + i;
        if (node < n) packed[node] = acc[i] + (1ull << 32);  // + self-loop (deg 1.0)
    }
}

// ---------------- fused dinv + block-level exclusive scan of cnt ----------------
__global__ void k_dinv_scan(const u64* __restrict__ packed, float* dinv, int* rowptr, int* bsum, int n) {
    __shared__ int s[256];
    int t = threadIdx.x;
    int i = blockIdx.x * 256 + t;
    u64 pk = (i < n) ? packed[i] : 0;
    if (i < n) {
        float deg = (float)(pk & 0xFFFFFFFFFFFFull) * DEG_INV;
        dinv[i] = rsqrtf(deg);
    }
    int v = (int)(pk >> 48);
    s[t] = v;
    __syncthreads();
    for (int off = 1; off < 256; off <<= 1) {
        int x = (t >= off) ? s[t - off] : 0;
        __syncthreads();
        s[t] += x;
        __syncthreads();
    }
    if (i < n) rowptr[i] = s[t] - v;  // exclusive
    if (t == 255) bsum[blockIdx.x] = s[255];
}

__global__ void k_scan_sums(int* bsum, int nb) {
    __shared__ int s[512];
    int t = threadIdx.x;
    int v = (t < nb) ? bsum[t] : 0;
    s[t] = v;
    __syncthreads();
    for (int off = 1; off < 512; off <<= 1) {
        int x = (t >= off) ? s[t - off] : 0;
        __syncthreads();
        s[t] += x;
        __syncthreads();
    }
    if (t < nb) bsum[t] = s[t] - v;  // exclusive
}

__global__ void k_scan_add(int* rowptr, const int* __restrict__ bsum, int n) {
    int i = blockIdx.x * 256 + threadIdx.x;
    if (i < n) rowptr[i] += bsum[blockIdx.x];
}

// ---------------- per-bucket scatter into CSR (L2-local rec writes) ----------------
__global__ __launch_bounds__(512) void k_bscatter(const u64* __restrict__ ebuf, const u32* __restrict__ bwptr,
                                                  const int* __restrict__ rowptr, const float* __restrict__ dinv,
                                                  int2* __restrict__ rec, int n) {
    __shared__ u32 fill[BSIZE];
    __shared__ int rp[BSIZE];
    __shared__ float din[BSIZE];
    int b = blockIdx.x;
    int t = threadIdx.x;
    int node0 = b << BSHIFT;
    for (int i = t; i < BSIZE; i += 512) {
        int node = node0 + i;
        fill[i] = 0;
        rp[i] = (node < n) ? rowptr[node] : 0;
        din[i] = (node < n) ? dinv[node] : 0.f;
    }
    __syncthreads();
    int cnt = (int)(bwptr[b] - (u32)b * CAP);
    const u64* eb = ebuf + (size_t)b * CAP;
    for (int e = t; e < cnt; e += 512) {
        u64 w = eb[e];
        u32 lo = (u32)w;
        int s = lo & 0x1FFFF;
        int dlow = (lo >> 17) & (BSIZE - 1);
        float ewv = __uint_as_float((u32)(w >> 32));
        float nrm = dinv[s] * ewv * din[dlow];
        int pos = rp[dlow] + (int)atomicAdd(&fill[dlow], 1u);
        rec[pos] = make_int2(s, __float_as_int(nrm));
    }
}

// ---------------- standalone gemm (layer 2) ----------------
template <typename TIn>
__global__ __launch_bounds__(256) void k_gemm(const TIn* __restrict__ A, const float* __restrict__ W,
                                              u16* __restrict__ outp, int n) {
    __shared__ float smem[2 * 32 * 128];
    gemm_block<TIn>(smem, A, W, outp, n, blockIdx.x);
}

// ---------------- aggregation: wave per node, half-wave per edge, lane = 4 channels ----------------
// MODE 0: write relu(agg)+bias to hout (bf16).  MODE 1: fused final FC -> out.
template <int MODE>
__global__ __launch_bounds__(256) void k_agg(const u16* __restrict__ t, const int2* __restrict__ rec,
                                             const int* __restrict__ rowptr, const u64* __restrict__ packed,
                                             const float* __restrict__ dinv, const float* __restrict__ bias,
                                             u16* __restrict__ hout,
                                             const float* __restrict__ action, const float* __restrict__ Wfc,
                                             const float* __restrict__ bfc, float* __restrict__ out, int n) {
    int node = blockIdx.x * 4 + (threadIdx.x >> 6);
    if (node >= n) return;
    int lane = threadIdx.x & 63;
    int half = lane >> 5;
    int c4 = (lane & 31) * 4;
    int base = rowptr[node];
    int m = (int)(packed[node] >> 48);

    float4 acc = make_float4(0.f, 0.f, 0.f, 0.f);
    int e = 0;
    for (; e + 8 <= m; e += 8) {
        int2 r0 = rec[base + e + 0 + half];
        int2 r1 = rec[base + e + 2 + half];
        int2 r2 = rec[base + e + 4 + half];
        int2 r3 = rec[base + e + 6 + half];
        ushort4 g0 = *reinterpret_cast<const ushort4*>(&t[(size_t)r0.x * 128 + c4]);
        ushort4 g1 = *reinterpret_cast<const ushort4*>(&t[(size_t)r1.x * 128 + c4]);
        ushort4 g2 = *reinterpret_cast<const ushort4*>(&t[(size_t)r2.x * 128 + c4]);
        ushort4 g3 = *reinterpret_cast<const ushort4*>(&t[(size_t)r3.x * 128 + c4]);
        float n0 = __int_as_float(r0.y), n1 = __int_as_float(r1.y);
        float n2 = __int_as_float(r2.y), n3 = __int_as_float(r3.y);
        acc.x = fmaf(n0, bf2f(g0.x), acc.x); acc.y = fmaf(n0, bf2f(g0.y), acc.y);
        acc.z = fmaf(n0, bf2f(g0.z), acc.z); acc.w = fmaf(n0, bf2f(g0.w), acc.w);
        acc.x = fmaf(n1, bf2f(g1.x), acc.x); acc.y = fmaf(n1, bf2f(g1.y), acc.y);
        acc.z = fmaf(n1, bf2f(g1.z), acc.z); acc.w = fmaf(n1, bf2f(g1.w), acc.w);
        acc.x = fmaf(n2, bf2f(g2.x), acc.x); acc.y = fmaf(n2, bf2f(g2.y), acc.y);
        acc.z = fmaf(n2, bf2f(g2.z), acc.z); acc.w = fmaf(n2, bf2f(g2.w), acc.w);
        acc.x = fmaf(n3, bf2f(g3.x), acc.x); acc.y = fmaf(n3, bf2f(g3.y), acc.y);
        acc.z = fmaf(n3, bf2f(g3.z), acc.z); acc.w = fmaf(n3, bf2f(g3.w), acc.w);
    }
    for (; e + 2 <= m; e += 2) {
        int2 r = rec[base + e + half];
        ushort4 g = *reinterpret_cast<const ushort4*>(&t[(size_t)r.x * 128 + c4]);
        float nn = __int_as_float(r.y);
        acc.x = fmaf(nn, bf2f(g.x), acc.x); acc.y = fmaf(nn, bf2f(g.y), acc.y);
        acc.z = fmaf(nn, bf2f(g.z), acc.z); acc.w = fmaf(nn, bf2f(g.w), acc.w);
    }
    if (e < m && half == 0) {
        int2 r = rec[base + e];
        ushort4 g = *reinterpret_cast<const ushort4*>(&t[(size_t)r.x * 128 + c4]);
        float nn = __int_as_float(r.y);
        acc.x = fmaf(nn, bf2f(g.x), acc.x); acc.y = fmaf(nn, bf2f(g.y), acc.y);
        acc.z = fmaf(nn, bf2f(g.z), acc.z); acc.w = fmaf(nn, bf2f(g.w), acc.w);
    }
    acc.x += __shfl_xor(acc.x, 32);
    acc.y += __shfl_xor(acc.y, 32);
    acc.z += __shfl_xor(acc.z, 32);
    acc.w += __shfl_xor(acc.w, 32);

    if (half == 0) {
        float di = dinv[node];
        float sdi = di * di;
        ushort4 sv = *reinterpret_cast<const ushort4*>(&t[(size_t)node * 128 + c4]);
        acc.x = fmaf(sdi, bf2f(sv.x), acc.x);
        acc.y = fmaf(sdi, bf2f(sv.y), acc.y);
        acc.z = fmaf(sdi, bf2f(sv.z), acc.z);
        acc.w = fmaf(sdi, bf2f(sv.w), acc.w);
        float4 b = *reinterpret_cast<const float4*>(&bias[c4]);
        acc.x = fmaxf(acc.x + b.x, 0.0f);
        acc.y = fmaxf(acc.y + b.y, 0.0f);
        acc.z = fmaxf(acc.z + b.z, 0.0f);
        acc.w = fmaxf(acc.w + b.w, 0.0f);
        if (MODE == 0) {
            ushort4 o;
            o.x = f2bf(acc.x); o.y = f2bf(acc.y); o.z = f2bf(acc.z); o.w = f2bf(acc.w);
            *reinterpret_cast<ushort4*>(&hout[(size_t)node * 128 + c4]) = o;
        } else {
            float4 w = *reinterpret_cast<const float4*>(&Wfc[c4]);
            float v = acc.x * w.x + acc.y * w.y + acc.z * w.z + acc.w * w.w;
#pragma unroll
            for (int off = 16; off >= 1; off >>= 1) v += __shfl_down(v, off, 32);
            if (lane == 0) out[node] = v + action[node] * Wfc[128] + bfc[0];
        }
    }
}

extern "C" void kernel_launch(void* const* d_in, const int* in_sizes, int n_in,
                              void* d_out, int out_size, void* d_ws, size_t ws_size,
                              hipStream_t stream) {
    const float* x = (const float*)d_in[0];
    const int* ei = (const int*)d_in[1];
    const float* ew = (const float*)d_in[2];
    const float* action = (const float*)d_in[3];
    const float* W1 = (const float*)d_in[4];
    const float* b1 = (const float*)d_in[5];
    const float* W2 = (const float*)d_in[6];
    const float* b2 = (const float*)d_in[7];
    const float* Wfc = (const float*)d_in[8];
    const float* bfc = (const float*)d_in[9];
    float* out = (float*)d_out;

    int n = in_sizes[0] / 128;
    int E = in_sizes[2];
    const int* src = ei;
    const int* dst = ei + E;

    char* p = (char*)d_ws;
    auto carve = [&](size_t bytes) -> char* {
        char* q = p;
        p += (bytes + 255) & ~(size_t)255;
        return q;
    };
    int NB = (n + BSIZE - 1) >> BSHIFT;      // 196 buckets
    u64* packed = (u64*)carve((size_t)n * 8);
    float* dinv = (float*)carve((size_t)n * 4);
    int* rowptr = (int*)carve((size_t)n * 4);
    int* bsum = (int*)carve(1024 * 4);
    u32* bwptr = (u32*)carve((size_t)NB * 4);
    u64* ebuf = (u64*)carve((size_t)NB * CAP * 8);
    int2* rec = (int2*)carve(((size_t)E + 16) * 8);
    u16* tbuf = (u16*)carve((size_t)n * 128 * 2);
    u16* hbuf = (u16*)carve((size_t)n * 128 * 2);

    int nb = (n + 255) / 256;
    int Gg = (n + 31) / 32;                  // 3125 gemm blocks
    int G = (Gg + 2) / 3;                    // 1042 groups of 5 blocks
    int Gp = 2 * G;                          // 2084 partition blocks
    int EPB = (E + Gp - 1) / Gp;             // ~1536 edges per partition block

    k_init0<<<1, 256, 0, stream>>>(bwptr, NB);
    k_part_gemm<<<G * 5, 256, 0, stream>>>(x, W1, tbuf, n, Gg, src, dst, ew,
                                           bwptr, ebuf, E, EPB, NB);
    k_bdegcnt<<<NB, 512, 0, stream>>>(ebuf, bwptr, packed, n);
    k_dinv_scan<<<nb, 256, 0, stream>>>(packed, dinv, rowptr, bsum, n);
    k_scan_sums<<<1, 512, 0, stream>>>(bsum, nb);
    k_scan_add<<<nb, 256, 0, stream>>>(rowptr, bsum, n);
    k_bscatter<<<NB, 512, 0, stream>>>(ebuf, bwptr, rowptr, dinv, rec, n);

    k_agg<0><<<(n + 3) / 4, 256, 0, stream>>>(tbuf, rec, rowptr, packed, dinv, b1, hbuf,
                                              nullptr, nullptr, nullptr, nullptr, n);
    k_gemm<u16><<<(n + 31) / 32, 256, 0, stream>>>(hbuf, W2, tbuf, n);
    k_agg<1><<<(n + 3) / 4, 256, 0, stream>>>(tbuf, rec, rowptr, packed, dinv, b2, nullptr,
                                              action, Wfc, bfc, out, n);
}